// Round 6
// baseline (759.062 us; speedup 1.0000x reference)
//
#include <hip/hip_runtime.h>
#include <hip/hip_bf16.h>

typedef __hip_bfloat16 bf16;

#define NVX 117000
#define NVR 117120         // rows padded to multiple of 64
#define NEX 468000
#define EMB 300
#define STR 320            // padded K/row stride for bf16 node buffers (pads zeroed)
#define NPAD 384           // padded N for node GEMM (3 tiles of 128)
#define IN_DIM 768
#define BATCH 4096
#define HID 500
#define FCK 1088           // FC1 K: [Hb row 0..319 | input 0..767]
#define HPAD 512           // FC hidden padded
#define NB 458             // scan blocks: ceil(NVX/256)
#define SSTR 328           // LDS row stride for fused layer (320 + 8 pad)

typedef __attribute__((ext_vector_type(8))) short frag8;   // 8 bf16 (4 VGPRs)
typedef __attribute__((ext_vector_type(4))) float f32x4;   // 4 fp32 acc

__device__ __forceinline__ float sigmoidf_(float x){ return 1.0f/(1.0f + __expf(-x)); }
__device__ __forceinline__ float bfs2f(short s){
  return __uint_as_float(((unsigned int)(unsigned short)s) << 16);
}
__device__ __forceinline__ short f2bfs(float f){
  bf16 b = __float2bfloat16(f);
  return *(short*)&b;
}

__device__ __forceinline__ void gload_lds16(const bf16* g, bf16* l){
  __builtin_amdgcn_global_load_lds((const __attribute__((address_space(1))) void*)g,
                                   (__attribute__((address_space(3))) void*)l, 16, 0, 0);
}

// ---------------- graph preprocessing ----------------

__global__ void k_deg(const int* __restrict__ erow, int* __restrict__ deg){
  int i = blockIdx.x*blockDim.x + threadIdx.x;
  if (i < NEX) atomicAdd(&deg[erow[i]], 1);
}

__global__ void k_dinv(const int* __restrict__ deg, float* __restrict__ dinv){
  int i = blockIdx.x*blockDim.x + threadIdx.x;
  if (i < NVX){ int d = deg[i]; dinv[i] = d > 0 ? rsqrtf((float)d) : 0.0f; }
}

__global__ __launch_bounds__(256) void k_partsum(const int* __restrict__ deg,
                                                 int* __restrict__ bsum){
  __shared__ int s[256];
  int t = threadIdx.x;
  int i = blockIdx.x*256 + t;
  s[t] = (i < NVX) ? deg[i] : 0;
  __syncthreads();
  #pragma unroll
  for (int off=128; off; off>>=1){
    if (t < off) s[t] += s[t+off];
    __syncthreads();
  }
  if (t == 0) bsum[blockIdx.x] = s[0];
}

__global__ __launch_bounds__(512) void k_scanb(const int* __restrict__ bsum,
                                               int* __restrict__ boff,
                                               int* __restrict__ rowptr){
  __shared__ int s[512];
  int t = threadIdx.x;
  int v = (t < NB) ? bsum[t] : 0;
  s[t] = v; __syncthreads();
  #pragma unroll
  for (int off=1; off<512; off<<=1){
    int u = (t>=off) ? s[t-off] : 0;
    __syncthreads();
    s[t] += u;
    __syncthreads();
  }
  if (t < NB) boff[t] = s[t] - v;
  if (t == 511) rowptr[NVX] = s[511];
}

__global__ __launch_bounds__(256) void k_writeptr(const int* __restrict__ deg,
                                                  const int* __restrict__ boff,
                                                  int* __restrict__ rowptr,
                                                  int* __restrict__ cursor){
  __shared__ int s[256];
  int t = threadIdx.x;
  int i = blockIdx.x*256 + t;
  int v = (i < NVX) ? deg[i] : 0;
  s[t] = v; __syncthreads();
  #pragma unroll
  for (int off=1; off<256; off<<=1){
    int u = (t>=off) ? s[t-off] : 0;
    __syncthreads();
    s[t] += u;
    __syncthreads();
  }
  if (i < NVX){
    int e = boff[blockIdx.x] + s[t] - v;
    rowptr[i] = e;
    cursor[i] = e;
  }
}

__global__ void k_scatter(const int* __restrict__ erow, const int* __restrict__ ecol,
                          const float* __restrict__ dinv, int* __restrict__ cursor,
                          int* __restrict__ ccol, float* __restrict__ cval){
  int i = blockIdx.x*blockDim.x + threadIdx.x;
  if (i < NEX){
    int r = erow[i], c = ecol[i];
    int p = atomicAdd(&cursor[r], 1);
    ccol[p] = c;
    cval[p] = dinv[r]*dinv[c];
  }
}

// H0 (f32 [NVX,300]) -> Xs (bf16 [NVR,320], pads zero). 4 cols per thread.
__global__ __launch_bounds__(256) void k_prepH(const float* __restrict__ H0,
                                               bf16* __restrict__ Xs){
  int i = blockIdx.x*256 + threadIdx.x;      // i = r*80 + g, g = col/4
  if (i >= NVR*80) return;
  int r = i / 80, g = i % 80;
  int c = g*4;
  short4 o;
  if (r < NVX && c < EMB){
    float4 v = *(const float4*)(H0 + (size_t)r*EMB + c);
    o.x = f2bfs(v.x); o.y = f2bfs(v.y); o.z = f2bfs(v.z); o.w = f2bfs(v.w);
  } else {
    o.x = o.y = o.z = o.w = 0;
  }
  *(short4*)(Xs + (size_t)r*STR + c) = o;
}

// all weight transposes/casts in one launch; job = blockIdx.y
// Wat k-mapping: k<300 -> Wa[k], 300..319 -> 0, 320.. -> Wa[k-20]  (FC1 A = [Hbrow|input])
__global__ __launch_bounds__(256) void k_prepWall(const float* __restrict__ W1,
                                                  const float* __restrict__ W2,
                                                  const float* __restrict__ Wa,
                                                  const float* __restrict__ Wb,
                                                  bf16* __restrict__ Wt1,
                                                  bf16* __restrict__ Wt2,
                                                  bf16* __restrict__ Wat,
                                                  bf16* __restrict__ Wbt){
  int job = blockIdx.y;
  int i = blockIdx.x*256 + threadIdx.x;
  if (job < 2){
    if (i >= NPAD*STR) return;
    int n = i / STR, k = i % STR;
    const float* W = job ? W2 : W1;
    bf16* o = job ? Wt2 : Wt1;
    float v = (n < EMB && k < EMB) ? W[k*EMB + n] : 0.0f;
    o[i] = __float2bfloat16(v);
  } else if (job == 2){
    if (i >= HPAD*FCK) return;
    int n = i / FCK, k = i % FCK;
    float v = 0.0f;
    if (n < HID){
      if (k < EMB)        v = Wa[(size_t)k*HID + n];
      else if (k >= STR)  v = Wa[(size_t)(k-(STR-EMB))*HID + n];
    }
    Wat[i] = __float2bfloat16(v);
  } else {
    if (i >= HPAD*HPAD) return;
    int n = i / HPAD, k = i % HPAD;
    float v = (n < HID && k < HID) ? Wb[(size_t)k*HID + n] : 0.0f;
    Wbt[i] = __float2bfloat16(v);
  }
}

// ---------------- fused GCN layer: Y = sigmoid( (LM @ X) @ W ) ----------------
// grid = NVR/64 blocks, 256 threads. Phase 1: gather-spmm 64 rows into LDS.
// Phase 2: MFMA vs W (L2-resident, B-frags read directly from global), epilogue sigmoid.
// Y pads (cols 300..319) written zero so downstream 16B-chunk gathers stay clean.

__global__ __launch_bounds__(256) void k_layer(const int* __restrict__ rowptr,
                                               const int* __restrict__ ccol,
                                               const float* __restrict__ cval,
                                               const bf16* __restrict__ X,
                                               const bf16* __restrict__ W,
                                               bf16* __restrict__ Y){
  __shared__ bf16 Ss[64*SSTR];
  const int tid  = threadIdx.x;
  const int wv   = tid >> 6;
  const int lane = tid & 63;
  const int row0 = blockIdx.x * 64;

  // ---- phase 1: spmm rows [row0, row0+64) -> Ss (lanes 0..39, 8 cols each) ----
  if (lane < 40){
    for (int rr = 0; rr < 16; ++rr){
      int m = wv*16 + rr;
      int r = row0 + m;
      float acc[8] = {0.f,0.f,0.f,0.f,0.f,0.f,0.f,0.f};
      if (r < NVX){
        int e0 = rowptr[r], e1 = rowptr[r+1];
        int e = e0;
        for (; e + 3 < e1; e += 4){
          float v0 = cval[e], v1 = cval[e+1], v2 = cval[e+2], v3 = cval[e+3];
          frag8 x0 = *(const frag8*)(X + (size_t)ccol[e  ]*STR + lane*8);
          frag8 x1 = *(const frag8*)(X + (size_t)ccol[e+1]*STR + lane*8);
          frag8 x2 = *(const frag8*)(X + (size_t)ccol[e+2]*STR + lane*8);
          frag8 x3 = *(const frag8*)(X + (size_t)ccol[e+3]*STR + lane*8);
          #pragma unroll
          for (int j=0;j<8;++j)
            acc[j] += v0*bfs2f(x0[j]) + v1*bfs2f(x1[j]) + v2*bfs2f(x2[j]) + v3*bfs2f(x3[j]);
        }
        for (; e < e1; ++e){
          float v0 = cval[e];
          frag8 x0 = *(const frag8*)(X + (size_t)ccol[e]*STR + lane*8);
          #pragma unroll
          for (int j=0;j<8;++j) acc[j] += v0*bfs2f(x0[j]);
        }
      }
      frag8 o;
      #pragma unroll
      for (int j=0;j<8;++j) o[j] = f2bfs(acc[j]);
      *(frag8*)(Ss + m*SSTR + lane*8) = o;
    }
  }
  __syncthreads();

  // ---- phase 2: C[64,384] = Ss @ W^T-layout, sigmoid, write Y ----
  const int wm = wv & 1, wn = wv >> 1;
  const int fr = lane & 15, fq = lane >> 4;
  for (int nt = 0; nt < 3; ++nt){
    int n0 = nt*128;
    f32x4 acc2[2][4];
    #pragma unroll
    for (int mi=0;mi<2;++mi)
      #pragma unroll
      for (int ni=0;ni<4;++ni) acc2[mi][ni] = (f32x4)(0.0f);
    #pragma unroll 2
    for (int k0 = 0; k0 < STR; k0 += 32){
      frag8 a[2], b[4];
      a[0] = *(const frag8*)(Ss + (wm*32 +      fr)*SSTR + k0 + fq*8);
      a[1] = *(const frag8*)(Ss + (wm*32 + 16 + fr)*SSTR + k0 + fq*8);
      #pragma unroll
      for (int ni=0;ni<4;++ni)
        b[ni] = *(const frag8*)(W + (size_t)(n0 + wn*64 + ni*16 + fr)*STR + k0 + fq*8);
      #pragma unroll
      for (int mi=0;mi<2;++mi)
        #pragma unroll
        for (int ni=0;ni<4;++ni)
          acc2[mi][ni] = __builtin_amdgcn_mfma_f32_16x16x32_bf16(a[mi], b[ni], acc2[mi][ni], 0, 0, 0);
    }
    #pragma unroll
    for (int mi=0;mi<2;++mi){
      int row = row0 + wm*32 + mi*16 + fq*4;
      #pragma unroll
      for (int ni=0;ni<4;++ni){
        int col = n0 + wn*64 + ni*16 + fr;
        if (col < STR){
          bf16* cp = Y + (size_t)row*STR + col;
          #pragma unroll
          for (int r=0;r<4;++r){
            float v = (col < EMB) ? sigmoidf_(acc2[mi][ni][r]) : 0.0f;
            cp[(size_t)r*STR] = __float2bfloat16(v);
          }
        }
      }
    }
  }
}

// ---------------- FC1 (fused gather): h1 = sigmoid([H2[node], input] @ Wa + ba) ----------------
// A k-layout: [0..319] = H2 row (pads zero), [320..1087] = input row. Wat matches.

__global__ __launch_bounds__(256) void k_fc1g(const bf16* __restrict__ H2,
                                              const int* __restrict__ node,
                                              const float* __restrict__ input,
                                              const bf16* __restrict__ Wat,
                                              const float* __restrict__ ba,
                                              bf16* __restrict__ h1){
  __shared__ bf16 As[128*32];
  __shared__ bf16 Bs[128*32];
  const int tid  = threadIdx.x;
  const int wv   = tid >> 6;
  const int lane = tid & 63;
  const int row0 = blockIdx.y * 128;
  const int n0   = blockIdx.x * 128;
  const int wm = wv & 1, wn = wv >> 1;
  const int srow = lane >> 2;
  const int schk = lane & 3;
  const int fr = lane & 15, fq = lane >> 4;

  const int nlo = node[row0 + wv*16 + srow];
  const int nhi = node[row0 + 64 + wv*16 + srow];

  f32x4 acc[4][4];
  #pragma unroll
  for (int i=0;i<4;++i)
    #pragma unroll
    for (int j=0;j<4;++j) acc[i][j] = (f32x4)(0.0f);

  for (int k0 = 0; k0 < FCK; k0 += 32){
    if (k0 < STR){
      gload_lds16(H2 + (size_t)nlo*STR + k0 + schk*8, As + wv*512 + lane*8);
      gload_lds16(H2 + (size_t)nhi*STR + k0 + schk*8, As + 2048 + wv*512 + lane*8);
    } else {
      int c = k0 - STR + schk*8;
      int m0 = wv*16 + srow;
      float4 u0 = *(const float4*)(input + (size_t)(row0+m0)*IN_DIM + c);
      float4 u1 = *(const float4*)(input + (size_t)(row0+m0)*IN_DIM + c + 4);
      frag8 t0;
      t0[0]=f2bfs(u0.x); t0[1]=f2bfs(u0.y); t0[2]=f2bfs(u0.z); t0[3]=f2bfs(u0.w);
      t0[4]=f2bfs(u1.x); t0[5]=f2bfs(u1.y); t0[6]=f2bfs(u1.z); t0[7]=f2bfs(u1.w);
      *(frag8*)(As + m0*32 + schk*8) = t0;
      int m1 = 64 + wv*16 + srow;
      float4 u2 = *(const float4*)(input + (size_t)(row0+m1)*IN_DIM + c);
      float4 u3 = *(const float4*)(input + (size_t)(row0+m1)*IN_DIM + c + 4);
      frag8 t1;
      t1[0]=f2bfs(u2.x); t1[1]=f2bfs(u2.y); t1[2]=f2bfs(u2.z); t1[3]=f2bfs(u2.w);
      t1[4]=f2bfs(u3.x); t1[5]=f2bfs(u3.y); t1[6]=f2bfs(u3.z); t1[7]=f2bfs(u3.w);
      *(frag8*)(As + m1*32 + schk*8) = t1;
    }
    gload_lds16(Wat + (size_t)(n0 + wv*16 + srow)*FCK + k0 + schk*8, Bs + wv*512 + lane*8);
    gload_lds16(Wat + (size_t)(n0 + 64 + wv*16 + srow)*FCK + k0 + schk*8, Bs + 2048 + wv*512 + lane*8);
    __syncthreads();
    frag8 a[4], b[4];
    #pragma unroll
    for (int mi=0;mi<4;++mi)
      a[mi] = *(const frag8*)(As + (wm*64 + mi*16 + fr)*32 + fq*8);
    #pragma unroll
    for (int ni=0;ni<4;++ni)
      b[ni] = *(const frag8*)(Bs + (wn*64 + ni*16 + fr)*32 + fq*8);
    #pragma unroll
    for (int mi=0;mi<4;++mi)
      #pragma unroll
      for (int ni=0;ni<4;++ni)
        acc[mi][ni] = __builtin_amdgcn_mfma_f32_16x16x32_bf16(a[mi], b[ni], acc[mi][ni], 0, 0, 0);
    __syncthreads();
  }

  #pragma unroll
  for (int mi=0;mi<4;++mi){
    int row = row0 + wm*64 + mi*16 + fq*4;
    #pragma unroll
    for (int ni=0;ni<4;++ni){
      int col = n0 + wn*64 + ni*16 + fr;
      float bv = (col < HID) ? ba[col] : 0.0f;
      bf16* cp = h1 + (size_t)row*HPAD + col;
      #pragma unroll
      for (int r=0;r<4;++r)
        cp[(size_t)r*HPAD] = __float2bfloat16(sigmoidf_(acc[mi][ni][r] + bv));
    }
  }
}

// ---------------- FC2 (m97-style MFMA): h2 = sigmoid(h1 @ Wb + bb), f32 out ----------------

__global__ __launch_bounds__(256) void k_fc2m(const bf16* __restrict__ A,
                                              const bf16* __restrict__ B,
                                              const float* __restrict__ bias,
                                              float* __restrict__ Cf){
  __shared__ bf16 As[128*32];
  __shared__ bf16 Bs[128*32];
  const int tid  = threadIdx.x;
  const int wv   = tid >> 6;
  const int lane = tid & 63;
  const int row0 = blockIdx.y * 128;
  const int n0   = blockIdx.x * 128;
  const int wm = wv & 1, wn = wv >> 1;
  const int srow = lane >> 2;
  const int schk = lane & 3;
  const int fr = lane & 15, fq = lane >> 4;

  f32x4 acc[4][4];
  #pragma unroll
  for (int i=0;i<4;++i)
    #pragma unroll
    for (int j=0;j<4;++j) acc[i][j] = (f32x4)(0.0f);

  for (int k0 = 0; k0 < HPAD; k0 += 32){
    const bf16* ag = A + (size_t)(row0 + wv*16 + srow)*HPAD + k0 + schk*8;
    gload_lds16(ag,            As + wv*512 + lane*8);
    gload_lds16(ag + 64*HPAD,  As + 2048 + wv*512 + lane*8);
    const bf16* bg = B + (size_t)(n0 + wv*16 + srow)*HPAD + k0 + schk*8;
    gload_lds16(bg,            Bs + wv*512 + lane*8);
    gload_lds16(bg + 64*HPAD,  Bs + 2048 + wv*512 + lane*8);
    __syncthreads();
    frag8 a[4], b[4];
    #pragma unroll
    for (int mi=0;mi<4;++mi)
      a[mi] = *(const frag8*)(As + (wm*64 + mi*16 + fr)*32 + fq*8);
    #pragma unroll
    for (int ni=0;ni<4;++ni)
      b[ni] = *(const frag8*)(Bs + (wn*64 + ni*16 + fr)*32 + fq*8);
    #pragma unroll
    for (int mi=0;mi<4;++mi)
      #pragma unroll
      for (int ni=0;ni<4;++ni)
        acc[mi][ni] = __builtin_amdgcn_mfma_f32_16x16x32_bf16(a[mi], b[ni], acc[mi][ni], 0, 0, 0);
    __syncthreads();
  }

  #pragma unroll
  for (int mi=0;mi<4;++mi){
    int row = row0 + wm*64 + mi*16 + fq*4;
    #pragma unroll
    for (int ni=0;ni<4;++ni){
      int col = n0 + wn*64 + ni*16 + fr;
      if (col < HID){
        float bv = bias[col];
        float* cp = Cf + (size_t)row*HID + col;
        #pragma unroll
        for (int r=0;r<4;++r)
          cp[(size_t)r*HID] = sigmoidf_(acc[mi][ni][r] + bv);
      }
    }
  }
}

// ---------------- FC3: out = h2 @ Wc + bc  (wave per batch row) ----------------

__global__ __launch_bounds__(256) void k_fc3(const float* __restrict__ h2,
                                             const float* __restrict__ Wc,
                                             const float* __restrict__ bc,
                                             float* __restrict__ out){
  int w = (int)((blockIdx.x*blockDim.x + threadIdx.x) >> 6);
  int lane = threadIdx.x & 63;
  if (w >= BATCH) return;
  const float* hr = h2 + (size_t)w*HID;
  float a0 = 0.f, a1 = 0.f;
  for (int k = lane; k < HID; k += 64){
    float h = hr[k];
    a0 += h * Wc[k*2+0];
    a1 += h * Wc[k*2+1];
  }
  #pragma unroll
  for (int off = 32; off; off >>= 1){
    a0 += __shfl_down(a0, off);
    a1 += __shfl_down(a1, off);
  }
  if (lane == 0){
    out[w*2+0] = a0 + bc[0];
    out[w*2+1] = a1 + bc[1];
  }
}

// ---------------- launch ----------------

extern "C" void kernel_launch(void* const* d_in, const int* in_sizes, int n_in,
                              void* d_out, int out_size, void* d_ws, size_t ws_size,
                              hipStream_t stream){
  const float* input = (const float*)d_in[0];
  const int*   node  = (const int*)d_in[1];
  const int*   erow  = (const int*)d_in[2];
  const int*   ecol  = (const int*)d_in[3];
  const float* H0    = (const float*)d_in[4];
  const float* W1    = (const float*)d_in[5];
  const float* W2    = (const float*)d_in[6];
  const float* Wa    = (const float*)d_in[7];
  const float* ba    = (const float*)d_in[8];
  const float* Wb    = (const float*)d_in[9];
  const float* bb    = (const float*)d_in[10];
  const float* Wc    = (const float*)d_in[11];
  const float* bc    = (const float*)d_in[12];

  char* p = (char*)d_ws;
  auto alloc = [&](size_t bytes)->char*{ char* r = p; p += (bytes + 255) & ~(size_t)255; return r; };
  int*   deg    = (int*)  alloc((size_t)NVX*4);
  float* dinv   = (float*)alloc((size_t)NVX*4);
  int*   rowptr = (int*)  alloc((size_t)(NVX+1)*4);
  int*   cursor = (int*)  alloc((size_t)NVX*4);
  int*   bsum   = (int*)  alloc((size_t)NB*4);
  int*   boff   = (int*)  alloc((size_t)NB*4);
  int*   ccol   = (int*)  alloc((size_t)NEX*4);
  float* cval   = (float*)alloc((size_t)NEX*4);
  bf16*  Xs     = (bf16*) alloc((size_t)NVR*STR*2);
  bf16*  Hb     = (bf16*) alloc((size_t)NVR*STR*2);
  bf16*  H2b    = (bf16*) alloc((size_t)NVR*STR*2);
  bf16*  Wt1    = (bf16*) alloc((size_t)NPAD*STR*2);
  bf16*  Wt2    = (bf16*) alloc((size_t)NPAD*STR*2);
  bf16*  Wat    = (bf16*) alloc((size_t)HPAD*FCK*2);
  bf16*  Wbt    = (bf16*) alloc((size_t)HPAD*HPAD*2);
  bf16*  h1     = (bf16*) alloc((size_t)BATCH*HPAD*2);
  float* h2     = (float*)alloc((size_t)BATCH*HID*4);

  hipMemsetAsync(deg, 0, (size_t)NVX*4, stream);
  k_deg     <<<(NEX+255)/256, 256, 0, stream>>>(erow, deg);
  k_dinv    <<<(NVX+255)/256, 256, 0, stream>>>(deg, dinv);
  k_partsum <<<NB, 256, 0, stream>>>(deg, bsum);
  k_scanb   <<<1, 512, 0, stream>>>(bsum, boff, rowptr);
  k_writeptr<<<NB, 256, 0, stream>>>(deg, boff, rowptr, cursor);
  k_scatter <<<(NEX+255)/256, 256, 0, stream>>>(erow, ecol, dinv, cursor, ccol, cval);
  k_prepH   <<<(NVR*80+255)/256, 256, 0, stream>>>(H0, Xs);
  k_prepWall<<<dim3((HPAD*FCK+255)/256, 4), 256, 0, stream>>>(W1, W2, Wa, Wb, Wt1, Wt2, Wat, Wbt);

  // fused GCN layers: H1 = sigmoid((LM@X)@W1), H2 = sigmoid((LM@H1)@W2)
  k_layer<<<NVR/64, 256, 0, stream>>>(rowptr, ccol, cval, Xs, Wt1, Hb);
  k_layer<<<NVR/64, 256, 0, stream>>>(rowptr, ccol, cval, Hb, Wt2, H2b);

  // FC stack
  k_fc1g<<<dim3(HPAD/128, BATCH/128), 256, 0, stream>>>(H2b, node, input, Wat, ba, h1);
  k_fc2m<<<dim3(HPAD/128, BATCH/128), 256, 0, stream>>>(h1, Wbt, bb, h2);
  k_fc3<<<BATCH/4, 256, 0, stream>>>(h2, Wc, bc, (float*)d_out);
}

// Round 7
// 589.427 us; speedup vs baseline: 1.2878x; 1.2878x over previous
//
#include <hip/hip_runtime.h>
#include <hip/hip_bf16.h>

typedef __hip_bfloat16 bf16;

#define NVX 117000
#define NVR 117120         // rows padded to multiple of 128
#define NEX 468000
#define EMB 300
#define STR 320            // padded K/row stride for bf16 node buffers (pads zeroed)
#define NPAD 384           // padded N for node GEMM (3 tiles of 128)
#define IN_DIM 768
#define BATCH 4096
#define HID 500
#define FCK 1088           // FC1 K: [H2 row 0..319 | input 0..767]
#define HPAD 512           // FC hidden padded
#define NB 458             // scan blocks: ceil(NVX/256)

typedef __attribute__((ext_vector_type(8))) short frag8;   // 8 bf16 (4 VGPRs)
typedef __attribute__((ext_vector_type(4))) float f32x4;   // 4 fp32 acc

__device__ __forceinline__ float sigmoidf_(float x){ return 1.0f/(1.0f + __expf(-x)); }
__device__ __forceinline__ float bfs2f(short s){
  return __uint_as_float(((unsigned int)(unsigned short)s) << 16);
}
__device__ __forceinline__ short f2bfs(float f){
  bf16 b = __float2bfloat16(f);
  return *(short*)&b;
}

__device__ __forceinline__ void gload_lds16(const bf16* g, bf16* l){
  __builtin_amdgcn_global_load_lds((const __attribute__((address_space(1))) void*)g,
                                   (__attribute__((address_space(3))) void*)l, 16, 0, 0);
}

// ---------------- graph preprocessing ----------------

__global__ void k_deg(const int* __restrict__ erow, int* __restrict__ deg){
  int i = blockIdx.x*blockDim.x + threadIdx.x;
  if (i < NEX) atomicAdd(&deg[erow[i]], 1);
}

__global__ void k_dinv(const int* __restrict__ deg, float* __restrict__ dinv){
  int i = blockIdx.x*blockDim.x + threadIdx.x;
  if (i < NVX){ int d = deg[i]; dinv[i] = d > 0 ? rsqrtf((float)d) : 0.0f; }
}

__global__ __launch_bounds__(256) void k_partsum(const int* __restrict__ deg,
                                                 int* __restrict__ bsum){
  __shared__ int s[256];
  int t = threadIdx.x;
  int i = blockIdx.x*256 + t;
  s[t] = (i < NVX) ? deg[i] : 0;
  __syncthreads();
  #pragma unroll
  for (int off=128; off; off>>=1){
    if (t < off) s[t] += s[t+off];
    __syncthreads();
  }
  if (t == 0) bsum[blockIdx.x] = s[0];
}

__global__ __launch_bounds__(512) void k_scanb(const int* __restrict__ bsum,
                                               int* __restrict__ boff,
                                               int* __restrict__ rowptr){
  __shared__ int s[512];
  int t = threadIdx.x;
  int v = (t < NB) ? bsum[t] : 0;
  s[t] = v; __syncthreads();
  #pragma unroll
  for (int off=1; off<512; off<<=1){
    int u = (t>=off) ? s[t-off] : 0;
    __syncthreads();
    s[t] += u;
    __syncthreads();
  }
  if (t < NB) boff[t] = s[t] - v;
  if (t == 511) rowptr[NVX] = s[511];
}

__global__ __launch_bounds__(256) void k_writeptr(const int* __restrict__ deg,
                                                  const int* __restrict__ boff,
                                                  int* __restrict__ rowptr,
                                                  int* __restrict__ cursor){
  __shared__ int s[256];
  int t = threadIdx.x;
  int i = blockIdx.x*256 + t;
  int v = (i < NVX) ? deg[i] : 0;
  s[t] = v; __syncthreads();
  #pragma unroll
  for (int off=1; off<256; off<<=1){
    int u = (t>=off) ? s[t-off] : 0;
    __syncthreads();
    s[t] += u;
    __syncthreads();
  }
  if (i < NVX){
    int e = boff[blockIdx.x] + s[t] - v;
    rowptr[i] = e;
    cursor[i] = e;
  }
}

__global__ void k_scatter(const int* __restrict__ erow, const int* __restrict__ ecol,
                          const float* __restrict__ dinv, int* __restrict__ cursor,
                          int* __restrict__ ccol, float* __restrict__ cval){
  int i = blockIdx.x*blockDim.x + threadIdx.x;
  if (i < NEX){
    int r = erow[i], c = ecol[i];
    int p = atomicAdd(&cursor[r], 1);
    ccol[p] = c;
    cval[p] = dinv[r]*dinv[c];
  }
}

// H0 (f32 [NVX,300]) -> Xs (bf16 [NVR,320], pads zero). 4 cols per thread.
__global__ __launch_bounds__(256) void k_prepH(const float* __restrict__ H0,
                                               bf16* __restrict__ Xs){
  int i = blockIdx.x*256 + threadIdx.x;      // i = r*80 + g, g = col/4
  if (i >= NVR*80) return;
  int r = i / 80, g = i % 80;
  int c = g*4;
  short4 o;
  if (r < NVX && c < EMB){
    float4 v = *(const float4*)(H0 + (size_t)r*EMB + c);
    o.x = f2bfs(v.x); o.y = f2bfs(v.y); o.z = f2bfs(v.z); o.w = f2bfs(v.w);
  } else {
    o.x = o.y = o.z = o.w = 0;
  }
  *(short4*)(Xs + (size_t)r*STR + c) = o;
}

// all weight transposes/casts in one launch; job = blockIdx.y
// Wat k-mapping: k<300 -> Wa[k], 300..319 -> 0, 320.. -> Wa[k-20]  (FC1 A = [H2row|input])
__global__ __launch_bounds__(256) void k_prepWall(const float* __restrict__ W1,
                                                  const float* __restrict__ W2,
                                                  const float* __restrict__ Wa,
                                                  const float* __restrict__ Wb,
                                                  bf16* __restrict__ Wt1,
                                                  bf16* __restrict__ Wt2,
                                                  bf16* __restrict__ Wat,
                                                  bf16* __restrict__ Wbt){
  int job = blockIdx.y;
  int i = blockIdx.x*256 + threadIdx.x;
  if (job < 2){
    if (i >= NPAD*STR) return;
    int n = i / STR, k = i % STR;
    const float* W = job ? W2 : W1;
    bf16* o = job ? Wt2 : Wt1;
    float v = (n < EMB && k < EMB) ? W[k*EMB + n] : 0.0f;
    o[i] = __float2bfloat16(v);
  } else if (job == 2){
    if (i >= HPAD*FCK) return;
    int n = i / FCK, k = i % FCK;
    float v = 0.0f;
    if (n < HID){
      if (k < EMB)        v = Wa[(size_t)k*HID + n];
      else if (k >= STR)  v = Wa[(size_t)(k-(STR-EMB))*HID + n];
    }
    Wat[i] = __float2bfloat16(v);
  } else {
    if (i >= HPAD*HPAD) return;
    int n = i / HPAD, k = i % HPAD;
    float v = (n < HID && k < HID) ? Wb[(size_t)k*HID + n] : 0.0f;
    Wbt[i] = __float2bfloat16(v);
  }
}

// ---------------- spmm (vectorized): Y[v,:] = sum_e val * X[col(e),:] ----------------
// wave per row; lanes 0..39 each own 8 contiguous cols (16 B vector load per edge).
// 4-edge unroll for outstanding-load ILP. X pad cols zero => Y pads zero.

__global__ __launch_bounds__(256) void k_spmm_v(const int* __restrict__ rowptr,
                                                const int* __restrict__ ccol,
                                                const float* __restrict__ cval,
                                                const bf16* __restrict__ X,
                                                bf16* __restrict__ Y){
  int w = (int)((blockIdx.x*blockDim.x + threadIdx.x) >> 6);
  int lane = threadIdx.x & 63;
  if (w >= NVR || lane >= 40) return;
  float acc[8] = {0.f,0.f,0.f,0.f,0.f,0.f,0.f,0.f};
  if (w < NVX){
    int e0 = rowptr[w], e1 = rowptr[w+1];
    int e = e0;
    for (; e + 3 < e1; e += 4){
      float v0 = cval[e], v1 = cval[e+1], v2 = cval[e+2], v3 = cval[e+3];
      frag8 x0 = *(const frag8*)(X + (size_t)ccol[e  ]*STR + lane*8);
      frag8 x1 = *(const frag8*)(X + (size_t)ccol[e+1]*STR + lane*8);
      frag8 x2 = *(const frag8*)(X + (size_t)ccol[e+2]*STR + lane*8);
      frag8 x3 = *(const frag8*)(X + (size_t)ccol[e+3]*STR + lane*8);
      #pragma unroll
      for (int j=0;j<8;++j)
        acc[j] += v0*bfs2f(x0[j]) + v1*bfs2f(x1[j]) + v2*bfs2f(x2[j]) + v3*bfs2f(x3[j]);
    }
    for (; e < e1; ++e){
      float v0 = cval[e];
      frag8 x0 = *(const frag8*)(X + (size_t)ccol[e]*STR + lane*8);
      #pragma unroll
      for (int j=0;j<8;++j) acc[j] += v0*bfs2f(x0[j]);
    }
  }
  frag8 o;
  #pragma unroll
  for (int j=0;j<8;++j) o[j] = f2bfs(acc[j]);
  *(frag8*)(Y + (size_t)w*STR + lane*8) = o;
}

// ---------------- node GEMM (MFMA): C = sigmoid(A @ W), pads zeroed ----------------
// grid = (NPAD/128, NVR/128). A [NVR][STR] bf16, Wt [NPAD][STR] bf16 (n-major).
// epilogue writes cols 300..319 as zero (so downstream 16B gathers stay clean).

__global__ __launch_bounds__(256) void k_gemm_node(const bf16* __restrict__ A,
                                                   const bf16* __restrict__ Wt,
                                                   bf16* __restrict__ C){
  __shared__ bf16 As[128*32];
  __shared__ bf16 Bs[128*32];
  const int tid  = threadIdx.x;
  const int wv   = tid >> 6;
  const int lane = tid & 63;
  const int row0 = blockIdx.y * 128;
  const int n0   = blockIdx.x * 128;
  const int wm = wv & 1, wn = wv >> 1;
  const int srow = lane >> 2;
  const int schk = lane & 3;
  const int fr = lane & 15, fq = lane >> 4;

  f32x4 acc[4][4];
  #pragma unroll
  for (int i=0;i<4;++i)
    #pragma unroll
    for (int j=0;j<4;++j) acc[i][j] = (f32x4)(0.0f);

  for (int k0 = 0; k0 < STR; k0 += 32){
    const bf16* ag = A + (size_t)(row0 + wv*16 + srow)*STR + k0 + schk*8;
    gload_lds16(ag,           As + wv*512 + lane*8);
    gload_lds16(ag + 64*STR,  As + 2048 + wv*512 + lane*8);
    const bf16* bg = Wt + (size_t)(n0 + wv*16 + srow)*STR + k0 + schk*8;
    gload_lds16(bg,           Bs + wv*512 + lane*8);
    gload_lds16(bg + 64*STR,  Bs + 2048 + wv*512 + lane*8);
    __syncthreads();
    frag8 a[4], b[4];
    #pragma unroll
    for (int mi=0;mi<4;++mi)
      a[mi] = *(const frag8*)(As + (wm*64 + mi*16 + fr)*32 + fq*8);
    #pragma unroll
    for (int ni=0;ni<4;++ni)
      b[ni] = *(const frag8*)(Bs + (wn*64 + ni*16 + fr)*32 + fq*8);
    #pragma unroll
    for (int mi=0;mi<4;++mi)
      #pragma unroll
      for (int ni=0;ni<4;++ni)
        acc[mi][ni] = __builtin_amdgcn_mfma_f32_16x16x32_bf16(a[mi], b[ni], acc[mi][ni], 0, 0, 0);
    __syncthreads();
  }

  // C/D layout col=lane&15, row=(lane>>4)*4+reg  [m89/m91-verified]
  #pragma unroll
  for (int mi=0;mi<4;++mi){
    int row = row0 + wm*64 + mi*16 + fq*4;
    #pragma unroll
    for (int ni=0;ni<4;++ni){
      int col = n0 + wn*64 + ni*16 + fr;
      if (col < STR){
        bf16* cp = C + (size_t)row*STR + col;
        #pragma unroll
        for (int r=0;r<4;++r){
          float v = (col < EMB) ? sigmoidf_(acc[mi][ni][r]) : 0.0f;
          cp[(size_t)r*STR] = __float2bfloat16(v);
        }
      }
    }
  }
}

// ---------------- FC1 (fused gather): h1 = sigmoid([H2[node], input] @ Wa + ba) ----------------
// A k-layout: [0..319] = H2 row (pads zero), [320..1087] = input row. Wat matches.

__global__ __launch_bounds__(256) void k_fc1g(const bf16* __restrict__ H2,
                                              const int* __restrict__ node,
                                              const float* __restrict__ input,
                                              const bf16* __restrict__ Wat,
                                              const float* __restrict__ ba,
                                              bf16* __restrict__ h1){
  __shared__ bf16 As[128*32];
  __shared__ bf16 Bs[128*32];
  const int tid  = threadIdx.x;
  const int wv   = tid >> 6;
  const int lane = tid & 63;
  const int row0 = blockIdx.y * 128;
  const int n0   = blockIdx.x * 128;
  const int wm = wv & 1, wn = wv >> 1;
  const int srow = lane >> 2;
  const int schk = lane & 3;
  const int fr = lane & 15, fq = lane >> 4;

  const int nlo = node[row0 + wv*16 + srow];
  const int nhi = node[row0 + 64 + wv*16 + srow];

  f32x4 acc[4][4];
  #pragma unroll
  for (int i=0;i<4;++i)
    #pragma unroll
    for (int j=0;j<4;++j) acc[i][j] = (f32x4)(0.0f);

  for (int k0 = 0; k0 < FCK; k0 += 32){
    if (k0 < STR){
      gload_lds16(H2 + (size_t)nlo*STR + k0 + schk*8, As + wv*512 + lane*8);
      gload_lds16(H2 + (size_t)nhi*STR + k0 + schk*8, As + 2048 + wv*512 + lane*8);
    } else {
      int c = k0 - STR + schk*8;
      int m0 = wv*16 + srow;
      float4 u0 = *(const float4*)(input + (size_t)(row0+m0)*IN_DIM + c);
      float4 u1 = *(const float4*)(input + (size_t)(row0+m0)*IN_DIM + c + 4);
      frag8 t0;
      t0[0]=f2bfs(u0.x); t0[1]=f2bfs(u0.y); t0[2]=f2bfs(u0.z); t0[3]=f2bfs(u0.w);
      t0[4]=f2bfs(u1.x); t0[5]=f2bfs(u1.y); t0[6]=f2bfs(u1.z); t0[7]=f2bfs(u1.w);
      *(frag8*)(As + m0*32 + schk*8) = t0;
      int m1 = 64 + wv*16 + srow;
      float4 u2 = *(const float4*)(input + (size_t)(row0+m1)*IN_DIM + c);
      float4 u3 = *(const float4*)(input + (size_t)(row0+m1)*IN_DIM + c + 4);
      frag8 t1;
      t1[0]=f2bfs(u2.x); t1[1]=f2bfs(u2.y); t1[2]=f2bfs(u2.z); t1[3]=f2bfs(u2.w);
      t1[4]=f2bfs(u3.x); t1[5]=f2bfs(u3.y); t1[6]=f2bfs(u3.z); t1[7]=f2bfs(u3.w);
      *(frag8*)(As + m1*32 + schk*8) = t1;
    }
    gload_lds16(Wat + (size_t)(n0 + wv*16 + srow)*FCK + k0 + schk*8, Bs + wv*512 + lane*8);
    gload_lds16(Wat + (size_t)(n0 + 64 + wv*16 + srow)*FCK + k0 + schk*8, Bs + 2048 + wv*512 + lane*8);
    __syncthreads();
    frag8 a[4], b[4];
    #pragma unroll
    for (int mi=0;mi<4;++mi)
      a[mi] = *(const frag8*)(As + (wm*64 + mi*16 + fr)*32 + fq*8);
    #pragma unroll
    for (int ni=0;ni<4;++ni)
      b[ni] = *(const frag8*)(Bs + (wn*64 + ni*16 + fr)*32 + fq*8);
    #pragma unroll
    for (int mi=0;mi<4;++mi)
      #pragma unroll
      for (int ni=0;ni<4;++ni)
        acc[mi][ni] = __builtin_amdgcn_mfma_f32_16x16x32_bf16(a[mi], b[ni], acc[mi][ni], 0, 0, 0);
    __syncthreads();
  }

  #pragma unroll
  for (int mi=0;mi<4;++mi){
    int row = row0 + wm*64 + mi*16 + fq*4;
    #pragma unroll
    for (int ni=0;ni<4;++ni){
      int col = n0 + wn*64 + ni*16 + fr;
      float bv = (col < HID) ? ba[col] : 0.0f;
      bf16* cp = h1 + (size_t)row*HPAD + col;
      #pragma unroll
      for (int r=0;r<4;++r)
        cp[(size_t)r*HPAD] = __float2bfloat16(sigmoidf_(acc[mi][ni][r] + bv));
    }
  }
}

// ---------------- FC2 (MFMA): h2 = sigmoid(h1 @ Wb + bb), f32 out ----------------

__global__ __launch_bounds__(256) void k_fc2m(const bf16* __restrict__ A,
                                              const bf16* __restrict__ B,
                                              const float* __restrict__ bias,
                                              float* __restrict__ Cf){
  __shared__ bf16 As[128*32];
  __shared__ bf16 Bs[128*32];
  const int tid  = threadIdx.x;
  const int wv   = tid >> 6;
  const int lane = tid & 63;
  const int row0 = blockIdx.y * 128;
  const int n0   = blockIdx.x * 128;
  const int wm = wv & 1, wn = wv >> 1;
  const int srow = lane >> 2;
  const int schk = lane & 3;
  const int fr = lane & 15, fq = lane >> 4;

  f32x4 acc[4][4];
  #pragma unroll
  for (int i=0;i<4;++i)
    #pragma unroll
    for (int j=0;j<4;++j) acc[i][j] = (f32x4)(0.0f);

  for (int k0 = 0; k0 < HPAD; k0 += 32){
    const bf16* ag = A + (size_t)(row0 + wv*16 + srow)*HPAD + k0 + schk*8;
    gload_lds16(ag,            As + wv*512 + lane*8);
    gload_lds16(ag + 64*HPAD,  As + 2048 + wv*512 + lane*8);
    const bf16* bg = B + (size_t)(n0 + wv*16 + srow)*HPAD + k0 + schk*8;
    gload_lds16(bg,            Bs + wv*512 + lane*8);
    gload_lds16(bg + 64*HPAD,  Bs + 2048 + wv*512 + lane*8);
    __syncthreads();
    frag8 a[4], b[4];
    #pragma unroll
    for (int mi=0;mi<4;++mi)
      a[mi] = *(const frag8*)(As + (wm*64 + mi*16 + fr)*32 + fq*8);
    #pragma unroll
    for (int ni=0;ni<4;++ni)
      b[ni] = *(const frag8*)(Bs + (wn*64 + ni*16 + fr)*32 + fq*8);
    #pragma unroll
    for (int mi=0;mi<4;++mi)
      #pragma unroll
      for (int ni=0;ni<4;++ni)
        acc[mi][ni] = __builtin_amdgcn_mfma_f32_16x16x32_bf16(a[mi], b[ni], acc[mi][ni], 0, 0, 0);
    __syncthreads();
  }

  #pragma unroll
  for (int mi=0;mi<4;++mi){
    int row = row0 + wm*64 + mi*16 + fq*4;
    #pragma unroll
    for (int ni=0;ni<4;++ni){
      int col = n0 + wn*64 + ni*16 + fr;
      if (col < HID){
        float bv = bias[col];
        float* cp = Cf + (size_t)row*HID + col;
        #pragma unroll
        for (int r=0;r<4;++r)
          cp[(size_t)r*HID] = sigmoidf_(acc[mi][ni][r] + bv);
      }
    }
  }
}

// ---------------- FC3: out = h2 @ Wc + bc  (wave per batch row) ----------------

__global__ __launch_bounds__(256) void k_fc3(const float* __restrict__ h2,
                                             const float* __restrict__ Wc,
                                             const float* __restrict__ bc,
                                             float* __restrict__ out){
  int w = (int)((blockIdx.x*blockDim.x + threadIdx.x) >> 6);
  int lane = threadIdx.x & 63;
  if (w >= BATCH) return;
  const float* hr = h2 + (size_t)w*HID;
  float a0 = 0.f, a1 = 0.f;
  for (int k = lane; k < HID; k += 64){
    float h = hr[k];
    a0 += h * Wc[k*2+0];
    a1 += h * Wc[k*2+1];
  }
  #pragma unroll
  for (int off = 32; off; off >>= 1){
    a0 += __shfl_down(a0, off);
    a1 += __shfl_down(a1, off);
  }
  if (lane == 0){
    out[w*2+0] = a0 + bc[0];
    out[w*2+1] = a1 + bc[1];
  }
}

// ---------------- launch ----------------

extern "C" void kernel_launch(void* const* d_in, const int* in_sizes, int n_in,
                              void* d_out, int out_size, void* d_ws, size_t ws_size,
                              hipStream_t stream){
  const float* input = (const float*)d_in[0];
  const int*   node  = (const int*)d_in[1];
  const int*   erow  = (const int*)d_in[2];
  const int*   ecol  = (const int*)d_in[3];
  const float* H0    = (const float*)d_in[4];
  const float* W1    = (const float*)d_in[5];
  const float* W2    = (const float*)d_in[6];
  const float* Wa    = (const float*)d_in[7];
  const float* ba    = (const float*)d_in[8];
  const float* Wb    = (const float*)d_in[9];
  const float* bb    = (const float*)d_in[10];
  const float* Wc    = (const float*)d_in[11];
  const float* bc    = (const float*)d_in[12];

  char* p = (char*)d_ws;
  auto alloc = [&](size_t bytes)->char*{ char* r = p; p += (bytes + 255) & ~(size_t)255; return r; };
  int*   deg    = (int*)  alloc((size_t)NVX*4);
  float* dinv   = (float*)alloc((size_t)NVX*4);
  int*   rowptr = (int*)  alloc((size_t)(NVX+1)*4);
  int*   cursor = (int*)  alloc((size_t)NVX*4);
  int*   bsum   = (int*)  alloc((size_t)NB*4);
  int*   boff   = (int*)  alloc((size_t)NB*4);
  int*   ccol   = (int*)  alloc((size_t)NEX*4);
  float* cval   = (float*)alloc((size_t)NEX*4);
  bf16*  Xs     = (bf16*) alloc((size_t)NVR*STR*2);   // H0 bf16, later reused as H2
  bf16*  G      = (bf16*) alloc((size_t)NVR*STR*2);   // spmm output
  bf16*  Hb     = (bf16*) alloc((size_t)NVR*STR*2);   // H1
  bf16*  Wt1    = (bf16*) alloc((size_t)NPAD*STR*2);
  bf16*  Wt2    = (bf16*) alloc((size_t)NPAD*STR*2);
  bf16*  Wat    = (bf16*) alloc((size_t)HPAD*FCK*2);
  bf16*  Wbt    = (bf16*) alloc((size_t)HPAD*HPAD*2);
  bf16*  h1     = (bf16*) alloc((size_t)BATCH*HPAD*2);
  float* h2     = (float*)alloc((size_t)BATCH*HID*4);

  hipMemsetAsync(deg, 0, (size_t)NVX*4, stream);
  k_deg     <<<(NEX+255)/256, 256, 0, stream>>>(erow, deg);
  k_dinv    <<<(NVX+255)/256, 256, 0, stream>>>(deg, dinv);
  k_partsum <<<NB, 256, 0, stream>>>(deg, bsum);
  k_scanb   <<<1, 512, 0, stream>>>(bsum, boff, rowptr);
  k_writeptr<<<NB, 256, 0, stream>>>(deg, boff, rowptr, cursor);
  k_scatter <<<(NEX+255)/256, 256, 0, stream>>>(erow, ecol, dinv, cursor, ccol, cval);
  k_prepH   <<<(NVR*80+255)/256, 256, 0, stream>>>(H0, Xs);
  k_prepWall<<<dim3((HPAD*FCK+255)/256, 4), 256, 0, stream>>>(W1, W2, Wa, Wb, Wt1, Wt2, Wat, Wbt);

  dim3 ggrid(NPAD/128, NVR/128);

  // layer 1: H1 = sigmoid((LM @ H0) @ W1)
  k_spmm_v   <<<NVR/4, 256, 0, stream>>>(rowptr, ccol, cval, Xs, G);
  k_gemm_node<<<ggrid, 256, 0, stream>>>(G, Wt1, Hb);
  // layer 2: H2 = sigmoid((LM @ H1) @ W2)   (H2 reuses Xs)
  k_spmm_v   <<<NVR/4, 256, 0, stream>>>(rowptr, ccol, cval, Hb, G);
  k_gemm_node<<<ggrid, 256, 0, stream>>>(G, Wt2, Xs);

  // FC stack
  k_fc1g<<<dim3(HPAD/128, BATCH/128), 256, 0, stream>>>(Xs, node, input, Wat, ba, h1);
  k_fc2m<<<dim3(HPAD/128, BATCH/128), 256, 0, stream>>>(h1, Wbt, bb, h2);
  k_fc3 <<<BATCH/4, 256, 0, stream>>>(h2, Wc, bc, (float*)d_out);
}